// Round 2
// baseline (252.259 us; speedup 1.0000x reference)
//
#include <hip/hip_runtime.h>
#include <hip/hip_bf16.h>

#define STAT_K 8
#define TOKEN_K 16

typedef short bf16x8 __attribute__((ext_vector_type(8)));
typedef float f32x4 __attribute__((ext_vector_type(4)));

__device__ inline ushort f2bf_rne(float x) {
    union { float f; unsigned u; } v; v.f = x;
    unsigned r = v.u + 0x7fff + ((v.u >> 16) & 1);
    return (ushort)(r >> 16);
}
__device__ inline float bf2f(ushort h) {
    union { unsigned u; float f; } v; v.u = ((unsigned)h) << 16;
    return v.f;
}

// ---------------------------------------------------------------------------
// K1: all five projection GEMMs in one launch, fp32 sources converted to
// bf16 (hi/lo where needed) on the fly during LDS staging; weights are
// transposed in LDS (paired-kk uint writes).
//   bid <  192 : split-precision 64x64-tile GEMMs (z=0 q@Wq_stat->q_stat,
//                z=1 sk@Wk_stat->k_stat, z=2 q@Wq_token->q_tokf), fp32 out.
//   bid >= 192 : token-path 64x256-tile GEMMs, hi-only bf16
//                (z2=0 token_keys(last16)@Wk_token->k_tok row-major,
//                 z2=1 values(last16)@Wv->v_projT per-head transposed).
// ---------------------------------------------------------------------------
__global__ __launch_bounds__(256) void fused_gemms(
    const float* __restrict__ queries, const float* __restrict__ stat_keys,
    const float* __restrict__ token_keys, const float* __restrict__ values,
    const float* __restrict__ Wq_stat, const float* __restrict__ Wk_stat,
    const float* __restrict__ Wq_token, const float* __restrict__ Wk_token,
    const float* __restrict__ Wv,
    float* __restrict__ q_stat, float* __restrict__ k_stat,
    float* __restrict__ q_tokf,
    ushort* __restrict__ k_tok, ushort* __restrict__ v_projT)
{
    __shared__ ushort smem[12800];   // 25.6 KB, unioned between variants
    const int tid = threadIdx.x;
    const int bid = blockIdx.x;
    const int wave = tid >> 6, lane = tid & 63;
    const int m16 = lane & 15, quad = lane >> 4;
    const int srow = tid >> 2, schunk = tid & 3;

    if (bid < 192) {
        // ---------------- split-precision 64x64 variant ----------------
        const int z = bid >> 6, t = bid & 63;
        const int row0 = (t >> 3) * 64, col0 = (t & 7) * 64;
        const float* A = (z == 1) ? stat_keys : queries;
        const float* W = (z == 0) ? Wq_stat : (z == 1) ? Wk_stat : Wq_token;
        float* C = (z == 0) ? q_stat : (z == 1) ? k_stat : q_tokf;

        ushort* As_hi = smem;            // [64][40]
        ushort* As_lo = smem + 2560;
        ushort* Bs_hi = smem + 5120;
        ushort* Bs_lo = smem + 7680;
        const int wm = wave & 1, wn = wave >> 1;
        const int bn0 = (tid & 15) * 4, bk2 = (tid >> 4) * 2;

        f32x4 acc[2][2];
        #pragma unroll
        for (int i = 0; i < 2; ++i)
            #pragma unroll
            for (int j = 0; j < 2; ++j)
                #pragma unroll
                for (int r = 0; r < 4; ++r) acc[i][j][r] = 0.f;

        for (int k0 = 0; k0 < 512; k0 += 32) {
            // A rows: 8 fp32 -> hi/lo bf16
            const float* ap = A + (size_t)(row0 + srow) * 512 + k0 + schunk * 8;
            float4 x0 = ((const float4*)ap)[0];
            float4 x1 = ((const float4*)ap)[1];
            ushort4 h0, l0, h1, l1;
            h0.x = f2bf_rne(x0.x); l0.x = f2bf_rne(x0.x - bf2f(h0.x));
            h0.y = f2bf_rne(x0.y); l0.y = f2bf_rne(x0.y - bf2f(h0.y));
            h0.z = f2bf_rne(x0.z); l0.z = f2bf_rne(x0.z - bf2f(h0.z));
            h0.w = f2bf_rne(x0.w); l0.w = f2bf_rne(x0.w - bf2f(h0.w));
            h1.x = f2bf_rne(x1.x); l1.x = f2bf_rne(x1.x - bf2f(h1.x));
            h1.y = f2bf_rne(x1.y); l1.y = f2bf_rne(x1.y - bf2f(h1.y));
            h1.z = f2bf_rne(x1.z); l1.z = f2bf_rne(x1.z - bf2f(h1.z));
            h1.w = f2bf_rne(x1.w); l1.w = f2bf_rne(x1.w - bf2f(h1.w));
            *(ushort4*)&As_hi[srow * 40 + schunk * 8]     = h0;
            *(ushort4*)&As_hi[srow * 40 + schunk * 8 + 4] = h1;
            *(ushort4*)&As_lo[srow * 40 + schunk * 8]     = l0;
            *(ushort4*)&As_lo[srow * 40 + schunk * 8 + 4] = l1;

            // B transpose: W[k][n] -> Bs[n][k], paired kk for 4B writes
            const float* wp = W + (size_t)(k0 + bk2) * 512 + col0 + bn0;
            float4 b0 = *(const float4*)wp;
            float4 b1 = *(const float4*)(wp + 512);
            const float* b0p = (const float*)&b0;
            const float* b1p = (const float*)&b1;
            #pragma unroll
            for (int j = 0; j < 4; ++j) {
                float v0 = b0p[j], v1 = b1p[j];
                ushort hh0 = f2bf_rne(v0), hh1 = f2bf_rne(v1);
                ushort ll0 = f2bf_rne(v0 - bf2f(hh0));
                ushort ll1 = f2bf_rne(v1 - bf2f(hh1));
                *(uint*)&Bs_hi[(bn0 + j) * 40 + bk2] = (uint)hh0 | ((uint)hh1 << 16);
                *(uint*)&Bs_lo[(bn0 + j) * 40 + bk2] = (uint)ll0 | ((uint)ll1 << 16);
            }
            __syncthreads();

            bf16x8 af[2], bfv[2], afl[2], bfl[2];
            #pragma unroll
            for (int i = 0; i < 2; ++i) {
                af[i]  = *(const bf16x8*)&As_hi[(wm * 32 + i * 16 + m16) * 40 + quad * 8];
                bfv[i] = *(const bf16x8*)&Bs_hi[(wn * 32 + i * 16 + m16) * 40 + quad * 8];
                afl[i] = *(const bf16x8*)&As_lo[(wm * 32 + i * 16 + m16) * 40 + quad * 8];
                bfl[i] = *(const bf16x8*)&Bs_lo[(wn * 32 + i * 16 + m16) * 40 + quad * 8];
            }
            #pragma unroll
            for (int i = 0; i < 2; ++i)
                #pragma unroll
                for (int j = 0; j < 2; ++j) {
                    acc[i][j] = __builtin_amdgcn_mfma_f32_16x16x32_bf16(af[i],  bfv[j], acc[i][j], 0, 0, 0);
                    acc[i][j] = __builtin_amdgcn_mfma_f32_16x16x32_bf16(af[i],  bfl[j], acc[i][j], 0, 0, 0);
                    acc[i][j] = __builtin_amdgcn_mfma_f32_16x16x32_bf16(afl[i], bfv[j], acc[i][j], 0, 0, 0);
                }
            __syncthreads();
        }

        #pragma unroll
        for (int i = 0; i < 2; ++i)
            #pragma unroll
            for (int j = 0; j < 2; ++j) {
                int r0 = row0 + wm * 32 + i * 16 + quad * 4;
                int c = col0 + wn * 32 + j * 16 + m16;
                #pragma unroll
                for (int reg = 0; reg < 4; ++reg)
                    C[(size_t)(r0 + reg) * 512 + c] = acc[i][j][reg];
            }
    } else {
        // ---------------- token-path 64x256 variant (hi only) ----------------
        const int u = bid - 192;
        const int z2 = u >> 8, vv = u & 255;
        const int col0 = (vv & 1) * 256, row0 = (vv >> 1) * 64;
        const float* A = z2 ? values : token_keys;
        const float* W = z2 ? Wv : Wk_token;

        ushort* As = smem;            // [64][40]
        ushort* Bs = smem + 2560;     // [256][40]
        const int r = row0 + srow;
        const size_t arow = (size_t)((r >> 4) * 64 + 48 + (r & 15)) * 512;
        const int n0 = (tid >> 2) * 4, kk8 = (tid & 3) * 8;

        f32x4 acc[4][4];
        #pragma unroll
        for (int i = 0; i < 4; ++i)
            #pragma unroll
            for (int j = 0; j < 4; ++j)
                #pragma unroll
                for (int rr = 0; rr < 4; ++rr) acc[i][j][rr] = 0.f;

        for (int k0 = 0; k0 < 512; k0 += 32) {
            // A rows: 8 fp32 -> bf16 hi
            const float* ap = A + arow + k0 + schunk * 8;
            float4 x0 = ((const float4*)ap)[0];
            float4 x1 = ((const float4*)ap)[1];
            ushort4 h0, h1;
            h0.x = f2bf_rne(x0.x); h0.y = f2bf_rne(x0.y);
            h0.z = f2bf_rne(x0.z); h0.w = f2bf_rne(x0.w);
            h1.x = f2bf_rne(x1.x); h1.y = f2bf_rne(x1.y);
            h1.z = f2bf_rne(x1.z); h1.w = f2bf_rne(x1.w);
            *(ushort4*)&As[srow * 40 + schunk * 8]     = h0;
            *(ushort4*)&As[srow * 40 + schunk * 8 + 4] = h1;

            // B transpose: 256n x 32k, 8 float4 loads, paired-kk uint writes
            const float* wb = W + (size_t)(k0 + kk8) * 512 + col0 + n0;
            float4 bb[8];
            #pragma unroll
            for (int rr = 0; rr < 8; ++rr) bb[rr] = *(const float4*)(wb + rr * 512);
            #pragma unroll
            for (int j = 0; j < 4; ++j) {
                #pragma unroll
                for (int p = 0; p < 4; ++p) {
                    float v0 = ((const float*)&bb[2 * p])[j];
                    float v1 = ((const float*)&bb[2 * p + 1])[j];
                    *(uint*)&Bs[(n0 + j) * 40 + kk8 + 2 * p] =
                        (uint)f2bf_rne(v0) | ((uint)f2bf_rne(v1) << 16);
                }
            }
            __syncthreads();

            bf16x8 af[4], bf[4];
            #pragma unroll
            for (int i = 0; i < 4; ++i) {
                af[i] = *(const bf16x8*)&As[(i * 16 + m16) * 40 + quad * 8];
                bf[i] = *(const bf16x8*)&Bs[(wave * 64 + i * 16 + m16) * 40 + quad * 8];
            }
            #pragma unroll
            for (int i = 0; i < 4; ++i)
                #pragma unroll
                for (int j = 0; j < 4; ++j)
                    acc[i][j] = __builtin_amdgcn_mfma_f32_16x16x32_bf16(af[i], bf[j], acc[i][j], 0, 0, 0);
            __syncthreads();
        }

        #pragma unroll
        for (int i = 0; i < 4; ++i)
            #pragma unroll
            for (int j = 0; j < 4; ++j) {
                int rg = row0 + i * 16 + quad * 4;
                int c = col0 + wave * 64 + j * 16 + m16;
                if (z2 == 0) {
                    #pragma unroll
                    for (int reg = 0; reg < 4; ++reg)
                        k_tok[(size_t)(rg + reg) * 512 + c] = f2bf_rne(acc[i][j][reg]);
                } else {
                    int bb2 = rg >> 10, st = rg & 1023;
                    int hh = c >> 6, dd = c & 63;
                    ushort4 o4;
                    o4.x = f2bf_rne(acc[i][j][0]);
                    o4.y = f2bf_rne(acc[i][j][1]);
                    o4.z = f2bf_rne(acc[i][j][2]);
                    o4.w = f2bf_rne(acc[i][j][3]);
                    *(ushort4*)(v_projT + (((size_t)((bb2 * 8 + hh) * 64 + dd)) << 10) + st) = o4;
                }
            }
    }
}

// ---------------------------------------------------------------------------
// K2: fused stat scoring/top-8/softmax + dense MFMA token attention.
// One block per (b,h,16-q slice); 4 waves. k_stat slice (16 KB) staged once
// in LDS and reused by all 16 q-rows; dense stat weights sw[q][s] live in
// LDS only. Phase B identical to the verified dense attention.
// ---------------------------------------------------------------------------
__global__ __launch_bounds__(256) void fused_attend(
    const float* __restrict__ q_tokf, const float* __restrict__ q_stat,
    const float* __restrict__ k_stat, const int* __restrict__ valid_lens,
    const ushort* __restrict__ k_tok, const ushort* __restrict__ v_projT,
    ushort* __restrict__ ctx_hi, ushort* __restrict__ ctx_lo)
{
    const int bid = blockIdx.x;
    const int bh = bid >> 2, qb = bid & 3;
    const int b = bh >> 3, h = bh & 7;
    const int tid = threadIdx.x, wave = tid >> 6, lane = tid & 63;
    const int l15 = lane & 15, g = lane >> 4;
    const int q0 = qb * 16;

    __shared__ float  ks[64][68];                     // k_stat slice fp32
    __shared__ float  qsf[16][68];                    // q_stat rows fp32
    __shared__ ushort qs_hi[16][72], qs_lo[16][72];   // q_tok hi/lo
    __shared__ float  sw[16][65];                     // dense stat weights
    __shared__ ushort comb_hi[16][264], comb_lo[16][264]; // [q][st], swizzled

    // ---- stage q_tok (split), q_stat, k_stat
    {
        const int qq = tid >> 4, c = (tid & 15) * 4;
        float4 x = *(const float4*)(q_tokf + (size_t)(b * 64 + q0 + qq) * 512 + h * 64 + c);
        ushort4 hx, lx;
        hx.x = f2bf_rne(x.x); lx.x = f2bf_rne(x.x - bf2f(hx.x));
        hx.y = f2bf_rne(x.y); lx.y = f2bf_rne(x.y - bf2f(hx.y));
        hx.z = f2bf_rne(x.z); lx.z = f2bf_rne(x.z - bf2f(hx.z));
        hx.w = f2bf_rne(x.w); lx.w = f2bf_rne(x.w - bf2f(hx.w));
        *(ushort4*)&qs_hi[qq][c] = hx;
        *(ushort4*)&qs_lo[qq][c] = lx;
        *(float4*)&qsf[qq][c] =
            *(const float4*)(q_stat + (size_t)(b * 64 + q0 + qq) * 512 + h * 64 + c);
        const int s = tid >> 2, c0 = (tid & 3) * 16;
        const float* kp = k_stat + (size_t)(b * 64 + s) * 512 + h * 64 + c0;
        #pragma unroll
        for (int i = 0; i < 4; ++i)
            *(float4*)&ks[s][c0 + 4 * i] = *(const float4*)(kp + 4 * i);
    }
    const int valid = valid_lens[b];
    __syncthreads();

    // ---- phase A: stat scores + top-8 + softmax (4 q-rows per wave)
    #pragma unroll
    for (int qi = 0; qi < 4; ++qi) {
        const int qq = wave * 4 + qi;
        const float4* kr = (const float4*)&ks[lane][0];
        const float4* qr = (const float4*)&qsf[qq][0];
        float sc = 0.f;
        #pragma unroll
        for (int i = 0; i < 16; ++i) {
            float4 a = qr[i], kk = kr[i];
            sc += a.x * kk.x + a.y * kk.y + a.z * kk.z + a.w * kk.w;
        }
        sc *= 0.125f;
        if (lane >= valid) sc = -1e6f;
        const float sc_keep = sc;
        float my = sc;
        bool picked = false;
        float m0 = 0.f, den = 0.f;
        #pragma unroll
        for (int j = 0; j < STAT_K; ++j) {
            float v = my;
            int idx = lane;
            #pragma unroll
            for (int off = 32; off > 0; off >>= 1) {
                float ov = __shfl_down(v, off);
                int   oi = __shfl_down(idx, off);
                if (ov > v || (ov == v && oi < idx)) { v = ov; idx = oi; }
            }
            v = __shfl(v, 0);
            idx = __shfl(idx, 0);
            if (j == 0) m0 = v;
            den += __expf(v - m0);
            if (lane == idx) { my = -3e38f; picked = true; }
        }
        sw[qq][lane] = picked ? __expf(sc_keep - m0) / den : 0.f;
    }
    __syncthreads();

    // ---- phase B: dense token attention (QK -> softmax -> comb -> PV)
    f32x4 accd;
    #pragma unroll
    for (int rr = 0; rr < 4; ++rr) accd[rr] = 0.f;

    const int swz = (l15 & 7) << 4;

    for (int ch = 0; ch < 4; ++ch) {
        const int sbase = ch * 16 + wave * 4;
        f32x4 sc[4];
        #pragma unroll
        for (int mt = 0; mt < 4; ++mt)
            #pragma unroll
            for (int rr = 0; rr < 4; ++rr) sc[mt][rr] = 0.f;

        #pragma unroll
        for (int ks2 = 0; ks2 < 2; ++ks2) {
            bf16x8 bhf = *(const bf16x8*)&qs_hi[l15][ks2 * 32 + g * 8];
            bf16x8 blf = *(const bf16x8*)&qs_lo[l15][ks2 * 32 + g * 8];
            #pragma unroll
            for (int mt = 0; mt < 4; ++mt) {
                const ushort* kp = k_tok +
                    (size_t)(b * 1024 + (sbase + mt) * 16 + l15) * 512 + h * 64 + ks2 * 32 + g * 8;
                bf16x8 a = *(const bf16x8*)kp;
                sc[mt] = __builtin_amdgcn_mfma_f32_16x16x32_bf16(a, bhf, sc[mt], 0, 0, 0);
                sc[mt] = __builtin_amdgcn_mfma_f32_16x16x32_bf16(a, blf, sc[mt], 0, 0, 0);
            }
        }

        #pragma unroll
        for (int mt = 0; mt < 4; ++mt) {
            float e0 = __expf(sc[mt][0] * 0.125f);
            float e1 = __expf(sc[mt][1] * 0.125f);
            float e2 = __expf(sc[mt][2] * 0.125f);
            float e3 = __expf(sc[mt][3] * 0.125f);
            float den = e0 + e1 + e2 + e3;
            den += __shfl_xor(den, 16);
            den += __shfl_xor(den, 32);
            float scl = sw[l15][sbase + mt] / den;
            ushort4 hx, lx;
            float c0 = e0 * scl; hx.x = f2bf_rne(c0); lx.x = f2bf_rne(c0 - bf2f(hx.x));
            float c1 = e1 * scl; hx.y = f2bf_rne(c1); lx.y = f2bf_rne(c1 - bf2f(hx.y));
            float c2 = e2 * scl; hx.z = f2bf_rne(c2); lx.z = f2bf_rne(c2 - bf2f(hx.z));
            float c3 = e3 * scl; hx.w = f2bf_rne(c3); lx.w = f2bf_rne(c3 - bf2f(hx.w));
            int colb = (((wave * 4 + mt) * 16 + g * 4) * 2) ^ swz;
            *(ushort4*)((char*)&comb_hi[l15][0] + colb) = hx;
            *(ushort4*)((char*)&comb_lo[l15][0] + colb) = lx;
        }
        __syncthreads();

        #pragma unroll
        for (int ks2 = 0; ks2 < 8; ++ks2) {
            const ushort* vp = v_projT +
                ((size_t)(bh * 64 + wave * 16 + l15) << 10) + ch * 256 + ks2 * 32 + g * 8;
            bf16x8 a = *(const bf16x8*)vp;
            int colb = ((ks2 * 32 + g * 8) * 2) ^ swz;
            bf16x8 bhf = *(const bf16x8*)((const char*)&comb_hi[l15][0] + colb);
            bf16x8 blf = *(const bf16x8*)((const char*)&comb_lo[l15][0] + colb);
            accd = __builtin_amdgcn_mfma_f32_16x16x32_bf16(a, bhf, accd, 0, 0, 0);
            accd = __builtin_amdgcn_mfma_f32_16x16x32_bf16(a, blf, accd, 0, 0, 0);
        }
        __syncthreads();
    }

    {
        size_t o = (size_t)(b * 64 + q0 + l15) * 512 + h * 64 + wave * 16 + g * 4;
        ushort4 hx, lx;
        #pragma unroll
        for (int rr = 0; rr < 4; ++rr) {
            ushort hh2 = f2bf_rne(accd[rr]);
            ((ushort*)&hx)[rr] = hh2;
            ((ushort*)&lx)[rr] = f2bf_rne(accd[rr] - bf2f(hh2));
        }
        *(ushort4*)(ctx_hi + o) = hx;
        *(ushort4*)(ctx_lo + o) = lx;
    }
}

// ---------------------------------------------------------------------------
// K3: out = ctx(hi/lo) @ Wo(hi/lo split on the fly), 512x512x512 -> fp32.
// ---------------------------------------------------------------------------
__global__ __launch_bounds__(256) void gemm_out_f(
    const ushort* __restrict__ Ah, const ushort* __restrict__ Al,
    const float* __restrict__ Wo, float* __restrict__ C)
{
    __shared__ ushort smem[10240];
    ushort* As_hi = smem;
    ushort* As_lo = smem + 2560;
    ushort* Bs_hi = smem + 5120;
    ushort* Bs_lo = smem + 7680;
    const int tid = threadIdx.x;
    const int row0 = blockIdx.y * 64, col0 = blockIdx.x * 64;
    const int wave = tid >> 6, lane = tid & 63;
    const int wm = wave & 1, wn = wave >> 1;
    const int m16 = lane & 15, quad = lane >> 4;
    const int srow = tid >> 2, schunk = tid & 3;
    const int bn0 = (tid & 15) * 4, bk2 = (tid >> 4) * 2;

    f32x4 acc[2][2];
    #pragma unroll
    for (int i = 0; i < 2; ++i)
        #pragma unroll
        for (int j = 0; j < 2; ++j)
            #pragma unroll
            for (int r = 0; r < 4; ++r) acc[i][j][r] = 0.f;

    for (int k0 = 0; k0 < 512; k0 += 32) {
        const size_t aoff = (size_t)(row0 + srow) * 512 + k0 + schunk * 8;
        *(uint4*)&As_hi[srow * 40 + schunk * 8] = *(const uint4*)(Ah + aoff);
        *(uint4*)&As_lo[srow * 40 + schunk * 8] = *(const uint4*)(Al + aoff);

        const float* wp = Wo + (size_t)(k0 + bk2) * 512 + col0 + bn0;
        float4 b0 = *(const float4*)wp;
        float4 b1 = *(const float4*)(wp + 512);
        const float* b0p = (const float*)&b0;
        const float* b1p = (const float*)&b1;
        #pragma unroll
        for (int j = 0; j < 4; ++j) {
            float v0 = b0p[j], v1 = b1p[j];
            ushort hh0 = f2bf_rne(v0), hh1 = f2bf_rne(v1);
            ushort ll0 = f2bf_rne(v0 - bf2f(hh0));
            ushort ll1 = f2bf_rne(v1 - bf2f(hh1));
            *(uint*)&Bs_hi[(bn0 + j) * 40 + bk2] = (uint)hh0 | ((uint)hh1 << 16);
            *(uint*)&Bs_lo[(bn0 + j) * 40 + bk2] = (uint)ll0 | ((uint)ll1 << 16);
        }
        __syncthreads();

        bf16x8 af[2], bfv[2], afl[2], bfl[2];
        #pragma unroll
        for (int i = 0; i < 2; ++i) {
            af[i]  = *(const bf16x8*)&As_hi[(wm * 32 + i * 16 + m16) * 40 + quad * 8];
            bfv[i] = *(const bf16x8*)&Bs_hi[(wn * 32 + i * 16 + m16) * 40 + quad * 8];
            afl[i] = *(const bf16x8*)&As_lo[(wm * 32 + i * 16 + m16) * 40 + quad * 8];
            bfl[i] = *(const bf16x8*)&Bs_lo[(wn * 32 + i * 16 + m16) * 40 + quad * 8];
        }
        #pragma unroll
        for (int i = 0; i < 2; ++i)
            #pragma unroll
            for (int j = 0; j < 2; ++j) {
                acc[i][j] = __builtin_amdgcn_mfma_f32_16x16x32_bf16(af[i],  bfv[j], acc[i][j], 0, 0, 0);
                acc[i][j] = __builtin_amdgcn_mfma_f32_16x16x32_bf16(af[i],  bfl[j], acc[i][j], 0, 0, 0);
                acc[i][j] = __builtin_amdgcn_mfma_f32_16x16x32_bf16(afl[i], bfv[j], acc[i][j], 0, 0, 0);
            }
        __syncthreads();
    }

    #pragma unroll
    for (int i = 0; i < 2; ++i)
        #pragma unroll
        for (int j = 0; j < 2; ++j) {
            int r0 = row0 + wm * 32 + i * 16 + quad * 4;
            int c = col0 + wn * 32 + j * 16 + m16;
            #pragma unroll
            for (int reg = 0; reg < 4; ++reg)
                C[(size_t)(r0 + reg) * 512 + c] = acc[i][j][reg];
        }
}

extern "C" void kernel_launch(void* const* d_in, const int* in_sizes, int n_in,
                              void* d_out, int out_size, void* d_ws, size_t ws_size,
                              hipStream_t stream) {
    const float* queries    = (const float*)d_in[0];
    const float* stat_keys  = (const float*)d_in[1];
    const float* token_keys = (const float*)d_in[2];
    const float* values     = (const float*)d_in[3];
    const int*   valid_lens = (const int*)d_in[4];
    const float* Wq_stat    = (const float*)d_in[5];
    const float* Wq_token   = (const float*)d_in[6];
    const float* Wk_stat    = (const float*)d_in[7];
    const float* Wk_token   = (const float*)d_in[8];
    const float* Wv         = (const float*)d_in[9];
    const float* Wo         = (const float*)d_in[10];

    char* w = (char*)d_ws;
    float*  q_stat  = (float*)(w + 0);           // 1 MB fp32 [512][512]
    float*  k_stat  = (float*)(w + 1048576);     // 1 MB
    float*  q_tokf  = (float*)(w + 2097152);     // 1 MB
    ushort* k_tok   = (ushort*)(w + 3145728);    // 8 MB bf16 [8192][512]
    ushort* v_projT = (ushort*)(w + 11534336);   // 8 MB bf16 [64][64][1024]
    ushort* ctx_hi  = (ushort*)(w + 19922944);   // 512 KB
    ushort* ctx_lo  = ctx_hi + 262144;           // 512 KB

    // K1: all projections (converts fused, weights transposed in LDS)
    fused_gemms<<<704, 256, 0, stream>>>(
        queries, stat_keys, token_keys, values,
        Wq_stat, Wk_stat, Wq_token, Wk_token, Wv,
        q_stat, k_stat, q_tokf, k_tok, v_projT);

    // K2: stat top-8 + softmax + dense token attention -> ctx hi/lo
    fused_attend<<<256, 256, 0, stream>>>(
        q_tokf, q_stat, k_stat, valid_lens, k_tok, v_projT, ctx_hi, ctx_lo);

    // K3: output projection
    gemm_out_f<<<dim3(8, 8), 256, 0, stream>>>(ctx_hi, ctx_lo, Wo, (float*)d_out);
}

// Round 4
// 221.989 us; speedup vs baseline: 1.1364x; 1.1364x over previous
//
#include <hip/hip_runtime.h>
#include <hip/hip_bf16.h>

#define STAT_K 8
#define TOKEN_K 16

typedef short bf16x8 __attribute__((ext_vector_type(8)));
typedef float f32x4 __attribute__((ext_vector_type(4)));

__device__ inline ushort f2bf_rne(float x) {
    union { float f; unsigned u; } v; v.f = x;
    unsigned r = v.u + 0x7fff + ((v.u >> 16) & 1);
    return (ushort)(r >> 16);
}
__device__ inline float bf2f(ushort h) {
    union { unsigned u; float f; } v; v.u = ((unsigned)h) << 16;
    return v.f;
}

// ---------------------------------------------------------------------------
// K1: transpose + hi/lo-split the 6 weight matrices (one 6 MB sweep).
// wT layout per z: hi[n][k] (262144 ush) then lo[n][k].
// ---------------------------------------------------------------------------
__global__ __launch_bounds__(256) void conv_w(
    const float* w0, const float* w1, const float* w2,
    const float* w3, const float* w4, const float* w5,
    ushort* wT)
{
    const int z = blockIdx.z;
    const float* srcs[6] = {w0, w1, w2, w3, w4, w5};
    const float* src = srcs[z];
    ushort* hi = wT + (size_t)z * 524288;
    ushort* lo = hi + 262144;
    __shared__ float t[32][33];
    const int c0 = blockIdx.x * 32, r0 = blockIdx.y * 32;
    const int tx = threadIdx.x & 31, ty = threadIdx.x >> 5;  // ty 0..7
    #pragma unroll
    for (int i = 0; i < 4; ++i)
        t[ty + 8 * i][tx] = src[(r0 + ty + 8 * i) * 512 + c0 + tx];
    __syncthreads();
    #pragma unroll
    for (int i = 0; i < 4; ++i) {
        float x = t[tx][ty + 8 * i];
        ushort h = f2bf_rne(x);
        int o = (c0 + ty + 8 * i) * 512 + r0 + tx;
        hi[o] = h;
        lo[o] = f2bf_rne(x - bf2f(h));
    }
}

// ---------------------------------------------------------------------------
// K2: all five projection GEMMs in one launch. Weights come PRE-transposed /
// PRE-split from conv_w (bf16 planes, conflict-free uint4 staging); only the
// small fp32 A operands are converted on the fly during LDS staging.
//   bid <  192 : split-precision 64x64 tiles (z=0 q@Wq_stat->q_stat,
//                z=1 sk@Wk_stat->k_stat, z=2 q@Wq_token->q_tokf), fp32 out.
//   bid >= 192 : token-path 64x256 tiles, hi-only bf16
//                (z2=0 token_keys(last16)@Wk_token->k_tok row-major,
//                 z2=1 values(last16)@Wv->v_projT per-head transposed).
// ---------------------------------------------------------------------------
__global__ __launch_bounds__(256) void gemm_all(
    const float* __restrict__ queries, const float* __restrict__ stat_keys,
    const float* __restrict__ token_keys, const float* __restrict__ values,
    const ushort* __restrict__ wT,
    float* __restrict__ q_stat, float* __restrict__ k_stat,
    float* __restrict__ q_tokf,
    ushort* __restrict__ k_tok, ushort* __restrict__ v_projT)
{
    __shared__ ushort smem[12800];   // 25.6 KB, unioned between variants
    const int tid = threadIdx.x;
    const int bid = blockIdx.x;
    const int wave = tid >> 6, lane = tid & 63;
    const int m16 = lane & 15, quad = lane >> 4;
    const int srow = tid >> 2, schunk = tid & 3;

    if (bid < 192) {
        // ---------------- split-precision 64x64 variant ----------------
        const int z = bid >> 6, t = bid & 63;
        const int row0 = (t >> 3) * 64, col0 = (t & 7) * 64;
        const float* A = (z == 1) ? stat_keys : queries;
        const ushort* Bh = wT + (size_t)z * 524288;
        const ushort* Bl = Bh + 262144;
        float* C = (z == 0) ? q_stat : (z == 1) ? k_stat : q_tokf;

        ushort* As_hi = smem;            // [64][40]
        ushort* As_lo = smem + 2560;
        ushort* Bs_hi = smem + 5120;
        ushort* Bs_lo = smem + 7680;
        const int wm = wave & 1, wn = wave >> 1;

        f32x4 acc[2][2];
        #pragma unroll
        for (int i = 0; i < 2; ++i)
            #pragma unroll
            for (int j = 0; j < 2; ++j)
                #pragma unroll
                for (int r = 0; r < 4; ++r) acc[i][j][r] = 0.f;

        for (int k0 = 0; k0 < 512; k0 += 32) {
            // A rows: 8 fp32 -> hi/lo bf16 on the fly
            const float* ap = A + (size_t)(row0 + srow) * 512 + k0 + schunk * 8;
            float4 x0 = ((const float4*)ap)[0];
            float4 x1 = ((const float4*)ap)[1];
            ushort4 h0, l0, h1, l1;
            h0.x = f2bf_rne(x0.x); l0.x = f2bf_rne(x0.x - bf2f(h0.x));
            h0.y = f2bf_rne(x0.y); l0.y = f2bf_rne(x0.y - bf2f(h0.y));
            h0.z = f2bf_rne(x0.z); l0.z = f2bf_rne(x0.z - bf2f(h0.z));
            h0.w = f2bf_rne(x0.w); l0.w = f2bf_rne(x0.w - bf2f(h0.w));
            h1.x = f2bf_rne(x1.x); l1.x = f2bf_rne(x1.x - bf2f(h1.x));
            h1.y = f2bf_rne(x1.y); l1.y = f2bf_rne(x1.y - bf2f(h1.y));
            h1.z = f2bf_rne(x1.z); l1.z = f2bf_rne(x1.z - bf2f(h1.z));
            h1.w = f2bf_rne(x1.w); l1.w = f2bf_rne(x1.w - bf2f(h1.w));
            *(ushort4*)&As_hi[srow * 40 + schunk * 8]     = h0;
            *(ushort4*)&As_hi[srow * 40 + schunk * 8 + 4] = h1;
            *(ushort4*)&As_lo[srow * 40 + schunk * 8]     = l0;
            *(ushort4*)&As_lo[srow * 40 + schunk * 8 + 4] = l1;

            // B: pre-split bf16 planes, straight uint4 -> ds_write_b128
            const size_t boff = (size_t)(col0 + srow) * 512 + k0 + schunk * 8;
            *(uint4*)&Bs_hi[srow * 40 + schunk * 8] = *(const uint4*)(Bh + boff);
            *(uint4*)&Bs_lo[srow * 40 + schunk * 8] = *(const uint4*)(Bl + boff);
            __syncthreads();

            bf16x8 af[2], bfv[2], afl[2], bfl[2];
            #pragma unroll
            for (int i = 0; i < 2; ++i) {
                af[i]  = *(const bf16x8*)&As_hi[(wm * 32 + i * 16 + m16) * 40 + quad * 8];
                bfv[i] = *(const bf16x8*)&Bs_hi[(wn * 32 + i * 16 + m16) * 40 + quad * 8];
                afl[i] = *(const bf16x8*)&As_lo[(wm * 32 + i * 16 + m16) * 40 + quad * 8];
                bfl[i] = *(const bf16x8*)&Bs_lo[(wn * 32 + i * 16 + m16) * 40 + quad * 8];
            }
            #pragma unroll
            for (int i = 0; i < 2; ++i)
                #pragma unroll
                for (int j = 0; j < 2; ++j) {
                    acc[i][j] = __builtin_amdgcn_mfma_f32_16x16x32_bf16(af[i],  bfv[j], acc[i][j], 0, 0, 0);
                    acc[i][j] = __builtin_amdgcn_mfma_f32_16x16x32_bf16(af[i],  bfl[j], acc[i][j], 0, 0, 0);
                    acc[i][j] = __builtin_amdgcn_mfma_f32_16x16x32_bf16(afl[i], bfv[j], acc[i][j], 0, 0, 0);
                }
            __syncthreads();
        }

        #pragma unroll
        for (int i = 0; i < 2; ++i)
            #pragma unroll
            for (int j = 0; j < 2; ++j) {
                int r0 = row0 + wm * 32 + i * 16 + quad * 4;
                int c = col0 + wn * 32 + j * 16 + m16;
                #pragma unroll
                for (int reg = 0; reg < 4; ++reg)
                    C[(size_t)(r0 + reg) * 512 + c] = acc[i][j][reg];
            }
    } else {
        // ---------------- token-path 64x256 variant (hi only) ----------------
        const int u = bid - 192;
        const int z2 = u >> 8, vv = u & 255;
        const int col0 = (vv & 1) * 256, row0 = (vv >> 1) * 64;
        const float* A = z2 ? values : token_keys;
        const ushort* Bh = wT + (size_t)(z2 ? 4 : 3) * 524288;  // hi planes of Wv / Wk_token

        ushort* As = smem;            // [64][40]
        ushort* Bs = smem + 2560;     // [256][40]
        const int r = row0 + srow;
        const size_t arow = (size_t)((r >> 4) * 64 + 48 + (r & 15)) * 512;

        f32x4 acc[4][4];
        #pragma unroll
        for (int i = 0; i < 4; ++i)
            #pragma unroll
            for (int j = 0; j < 4; ++j)
                #pragma unroll
                for (int rr = 0; rr < 4; ++rr) acc[i][j][rr] = 0.f;

        for (int k0 = 0; k0 < 512; k0 += 32) {
            // A rows: 8 fp32 -> bf16 hi on the fly
            const float* ap = A + arow + k0 + schunk * 8;
            float4 x0 = ((const float4*)ap)[0];
            float4 x1 = ((const float4*)ap)[1];
            ushort4 h0, h1;
            h0.x = f2bf_rne(x0.x); h0.y = f2bf_rne(x0.y);
            h0.z = f2bf_rne(x0.z); h0.w = f2bf_rne(x0.w);
            h1.x = f2bf_rne(x1.x); h1.y = f2bf_rne(x1.y);
            h1.z = f2bf_rne(x1.z); h1.w = f2bf_rne(x1.w);
            *(ushort4*)&As[srow * 40 + schunk * 8]     = h0;
            *(ushort4*)&As[srow * 40 + schunk * 8 + 4] = h1;

            // B: pre-split bf16 hi plane, 4 uint4/thread
            #pragma unroll
            for (int i = 0; i < 4; ++i) {
                int v = tid + i * 256;
                int brow = v >> 2, bchunk = v & 3;
                *(uint4*)&Bs[brow * 40 + bchunk * 8] =
                    *(const uint4*)(Bh + (size_t)(col0 + brow) * 512 + k0 + bchunk * 8);
            }
            __syncthreads();

            bf16x8 af[4], bf[4];
            #pragma unroll
            for (int i = 0; i < 4; ++i) {
                af[i] = *(const bf16x8*)&As[(i * 16 + m16) * 40 + quad * 8];
                bf[i] = *(const bf16x8*)&Bs[(wave * 64 + i * 16 + m16) * 40 + quad * 8];
            }
            #pragma unroll
            for (int i = 0; i < 4; ++i)
                #pragma unroll
                for (int j = 0; j < 4; ++j)
                    acc[i][j] = __builtin_amdgcn_mfma_f32_16x16x32_bf16(af[i], bf[j], acc[i][j], 0, 0, 0);
            __syncthreads();
        }

        #pragma unroll
        for (int i = 0; i < 4; ++i)
            #pragma unroll
            for (int j = 0; j < 4; ++j) {
                int rg = row0 + i * 16 + quad * 4;
                int c = col0 + wave * 64 + j * 16 + m16;
                if (z2 == 0) {
                    #pragma unroll
                    for (int reg = 0; reg < 4; ++reg)
                        k_tok[(size_t)(rg + reg) * 512 + c] = f2bf_rne(acc[i][j][reg]);
                } else {
                    int bb2 = rg >> 10, st = rg & 1023;
                    int hh = c >> 6, dd = c & 63;
                    ushort4 o4;
                    o4.x = f2bf_rne(acc[i][j][0]);
                    o4.y = f2bf_rne(acc[i][j][1]);
                    o4.z = f2bf_rne(acc[i][j][2]);
                    o4.w = f2bf_rne(acc[i][j][3]);
                    *(ushort4*)(v_projT + (((size_t)((bb2 * 8 + hh) * 64 + dd)) << 10) + st) = o4;
                }
            }
    }
}

// ---------------------------------------------------------------------------
// K3: fused stat scoring/top-8/softmax + dense MFMA token attention.
// One block per (b,h,16-q slice); 4 waves. (verified in round 2)
// ---------------------------------------------------------------------------
__global__ __launch_bounds__(256) void fused_attend(
    const float* __restrict__ q_tokf, const float* __restrict__ q_stat,
    const float* __restrict__ k_stat, const int* __restrict__ valid_lens,
    const ushort* __restrict__ k_tok, const ushort* __restrict__ v_projT,
    ushort* __restrict__ ctx_hi, ushort* __restrict__ ctx_lo)
{
    const int bid = blockIdx.x;
    const int bh = bid >> 2, qb = bid & 3;
    const int b = bh >> 3, h = bh & 7;
    const int tid = threadIdx.x, wave = tid >> 6, lane = tid & 63;
    const int l15 = lane & 15, g = lane >> 4;
    const int q0 = qb * 16;

    __shared__ float  ks[64][68];                     // k_stat slice fp32
    __shared__ float  qsf[16][68];                    // q_stat rows fp32
    __shared__ ushort qs_hi[16][72], qs_lo[16][72];   // q_tok hi/lo
    __shared__ float  sw[16][65];                     // dense stat weights
    __shared__ ushort comb_hi[16][264], comb_lo[16][264]; // [q][st], swizzled

    // ---- stage q_tok (split), q_stat, k_stat
    {
        const int qq = tid >> 4, c = (tid & 15) * 4;
        float4 x = *(const float4*)(q_tokf + (size_t)(b * 64 + q0 + qq) * 512 + h * 64 + c);
        ushort4 hx, lx;
        hx.x = f2bf_rne(x.x); lx.x = f2bf_rne(x.x - bf2f(hx.x));
        hx.y = f2bf_rne(x.y); lx.y = f2bf_rne(x.y - bf2f(hx.y));
        hx.z = f2bf_rne(x.z); lx.z = f2bf_rne(x.z - bf2f(hx.z));
        hx.w = f2bf_rne(x.w); lx.w = f2bf_rne(x.w - bf2f(hx.w));
        *(ushort4*)&qs_hi[qq][c] = hx;
        *(ushort4*)&qs_lo[qq][c] = lx;
        *(float4*)&qsf[qq][c] =
            *(const float4*)(q_stat + (size_t)(b * 64 + q0 + qq) * 512 + h * 64 + c);
        const int s = tid >> 2, c0 = (tid & 3) * 16;
        const float* kp = k_stat + (size_t)(b * 64 + s) * 512 + h * 64 + c0;
        #pragma unroll
        for (int i = 0; i < 4; ++i)
            *(float4*)&ks[s][c0 + 4 * i] = *(const float4*)(kp + 4 * i);
    }
    const int valid = valid_lens[b];
    __syncthreads();

    // ---- phase A: stat scores + top-8 + softmax (4 q-rows per wave)
    #pragma unroll
    for (int qi = 0; qi < 4; ++qi) {
        const int qq = wave * 4 + qi;
        const float4* kr = (const float4*)&ks[lane][0];
        const float4* qr = (const float4*)&qsf[qq][0];
        float sc = 0.f;
        #pragma unroll
        for (int i = 0; i < 16; ++i) {
            float4 a = qr[i], kk = kr[i];
            sc += a.x * kk.x + a.y * kk.y + a.z * kk.z + a.w * kk.w;
        }
        sc *= 0.125f;
        if (lane >= valid) sc = -1e6f;
        const float sc_keep = sc;
        float my = sc;
        bool picked = false;
        float m0 = 0.f, den = 0.f;
        #pragma unroll
        for (int j = 0; j < STAT_K; ++j) {
            float v = my;
            int idx = lane;
            #pragma unroll
            for (int off = 32; off > 0; off >>= 1) {
                float ov = __shfl_down(v, off);
                int   oi = __shfl_down(idx, off);
                if (ov > v || (ov == v && oi < idx)) { v = ov; idx = oi; }
            }
            v = __shfl(v, 0);
            idx = __shfl(idx, 0);
            if (j == 0) m0 = v;
            den += __expf(v - m0);
            if (lane == idx) { my = -3e38f; picked = true; }
        }
        sw[qq][lane] = picked ? __expf(sc_keep - m0) / den : 0.f;
    }
    __syncthreads();

    // ---- phase B: dense token attention (QK -> softmax -> comb -> PV)
    f32x4 accd;
    #pragma unroll
    for (int rr = 0; rr < 4; ++rr) accd[rr] = 0.f;

    const int swz = (l15 & 7) << 4;

    for (int ch = 0; ch < 4; ++ch) {
        const int sbase = ch * 16 + wave * 4;
        f32x4 sc[4];
        #pragma unroll
        for (int mt = 0; mt < 4; ++mt)
            #pragma unroll
            for (int rr = 0; rr < 4; ++rr) sc[mt][rr] = 0.f;

        #pragma unroll
        for (int ks2 = 0; ks2 < 2; ++ks2) {
            bf16x8 bhf = *(const bf16x8*)&qs_hi[l15][ks2 * 32 + g * 8];
            bf16x8 blf = *(const bf16x8*)&qs_lo[l15][ks2 * 32 + g * 8];
            #pragma unroll
            for (int mt = 0; mt < 4; ++mt) {
                const ushort* kp = k_tok +
                    (size_t)(b * 1024 + (sbase + mt) * 16 + l15) * 512 + h * 64 + ks2 * 32 + g * 8;
                bf16x8 a = *(const bf16x8*)kp;
                sc[mt] = __builtin_amdgcn_mfma_f32_16x16x32_bf16(a, bhf, sc[mt], 0, 0, 0);
                sc[mt] = __builtin_amdgcn_mfma_f32_16x16x32_bf16(a, blf, sc[mt], 0, 0, 0);
            }
        }

        #pragma unroll
        for (int mt = 0; mt < 4; ++mt) {
            float e0 = __expf(sc[mt][0] * 0.125f);
            float e1 = __expf(sc[mt][1] * 0.125f);
            float e2 = __expf(sc[mt][2] * 0.125f);
            float e3 = __expf(sc[mt][3] * 0.125f);
            float den = e0 + e1 + e2 + e3;
            den += __shfl_xor(den, 16);
            den += __shfl_xor(den, 32);
            float scl = sw[l15][sbase + mt] / den;
            ushort4 hx, lx;
            float c0 = e0 * scl; hx.x = f2bf_rne(c0); lx.x = f2bf_rne(c0 - bf2f(hx.x));
            float c1 = e1 * scl; hx.y = f2bf_rne(c1); lx.y = f2bf_rne(c1 - bf2f(hx.y));
            float c2 = e2 * scl; hx.z = f2bf_rne(c2); lx.z = f2bf_rne(c2 - bf2f(hx.z));
            float c3 = e3 * scl; hx.w = f2bf_rne(c3); lx.w = f2bf_rne(c3 - bf2f(hx.w));
            int colb = (((wave * 4 + mt) * 16 + g * 4) * 2) ^ swz;
            *(ushort4*)((char*)&comb_hi[l15][0] + colb) = hx;
            *(ushort4*)((char*)&comb_lo[l15][0] + colb) = lx;
        }
        __syncthreads();

        #pragma unroll
        for (int ks2 = 0; ks2 < 8; ++ks2) {
            const ushort* vp = v_projT +
                ((size_t)(bh * 64 + wave * 16 + l15) << 10) + ch * 256 + ks2 * 32 + g * 8;
            bf16x8 a = *(const bf16x8*)vp;
            int colb = ((ks2 * 32 + g * 8) * 2) ^ swz;
            bf16x8 bhf = *(const bf16x8*)((const char*)&comb_hi[l15][0] + colb);
            bf16x8 blf = *(const bf16x8*)((const char*)&comb_lo[l15][0] + colb);
            accd = __builtin_amdgcn_mfma_f32_16x16x32_bf16(a, bhf, accd, 0, 0, 0);
            accd = __builtin_amdgcn_mfma_f32_16x16x32_bf16(a, blf, accd, 0, 0, 0);
        }
        __syncthreads();
    }

    {
        size_t o = (size_t)(b * 64 + q0 + l15) * 512 + h * 64 + wave * 16 + g * 4;
        ushort4 hx, lx;
        #pragma unroll
        for (int rr = 0; rr < 4; ++rr) {
            ushort hh2 = f2bf_rne(accd[rr]);
            ((ushort*)&hx)[rr] = hh2;
            ((ushort*)&lx)[rr] = f2bf_rne(accd[rr] - bf2f(hh2));
        }
        *(ushort4*)(ctx_hi + o) = hx;
        *(ushort4*)(ctx_lo + o) = lx;
    }
}

// ---------------------------------------------------------------------------
// K4: out = ctx(hi/lo) @ Wo(hi/lo planes from conv_w), 512x512x512 -> fp32.
// ---------------------------------------------------------------------------
__global__ __launch_bounds__(256) void gemm_out(
    const ushort* __restrict__ Ah, const ushort* __restrict__ Al,
    const ushort* __restrict__ Bh, const ushort* __restrict__ Bl,
    float* __restrict__ C)
{
    __shared__ ushort As[2][64][40];
    __shared__ ushort Bs[2][64][40];
    const int tid = threadIdx.x;
    const int row0 = blockIdx.y * 64, col0 = blockIdx.x * 64;
    const int wave = tid >> 6, lane = tid & 63;
    const int wm = wave & 1, wn = wave >> 1;
    const int m16 = lane & 15, quad = lane >> 4;
    const int srow = tid >> 2, schunk = tid & 3;

    f32x4 acc[2][2];
    #pragma unroll
    for (int i = 0; i < 2; ++i)
        #pragma unroll
        for (int j = 0; j < 2; ++j)
            #pragma unroll
            for (int r = 0; r < 4; ++r) acc[i][j][r] = 0.f;

    for (int k0 = 0; k0 < 512; k0 += 32) {
        const size_t aoff = (size_t)(row0 + srow) * 512 + k0 + schunk * 8;
        const size_t boff = (size_t)(col0 + srow) * 512 + k0 + schunk * 8;
        *(uint4*)&As[0][srow][schunk * 8] = *(const uint4*)(Ah + aoff);
        *(uint4*)&Bs[0][srow][schunk * 8] = *(const uint4*)(Bh + boff);
        *(uint4*)&As[1][srow][schunk * 8] = *(const uint4*)(Al + aoff);
        *(uint4*)&Bs[1][srow][schunk * 8] = *(const uint4*)(Bl + boff);
        __syncthreads();

        bf16x8 af[2], bf[2], afl[2], bfl[2];
        #pragma unroll
        for (int i = 0; i < 2; ++i) {
            af[i]  = *(const bf16x8*)&As[0][wm * 32 + i * 16 + m16][quad * 8];
            bf[i]  = *(const bf16x8*)&Bs[0][wn * 32 + i * 16 + m16][quad * 8];
            afl[i] = *(const bf16x8*)&As[1][wm * 32 + i * 16 + m16][quad * 8];
            bfl[i] = *(const bf16x8*)&Bs[1][wn * 32 + i * 16 + m16][quad * 8];
        }
        #pragma unroll
        for (int i = 0; i < 2; ++i)
            #pragma unroll
            for (int j = 0; j < 2; ++j) {
                acc[i][j] = __builtin_amdgcn_mfma_f32_16x16x32_bf16(af[i], bf[j], acc[i][j], 0, 0, 0);
                acc[i][j] = __builtin_amdgcn_mfma_f32_16x16x32_bf16(af[i], bfl[j], acc[i][j], 0, 0, 0);
                acc[i][j] = __builtin_amdgcn_mfma_f32_16x16x32_bf16(afl[i], bf[j], acc[i][j], 0, 0, 0);
            }
        __syncthreads();
    }

    #pragma unroll
    for (int i = 0; i < 2; ++i)
        #pragma unroll
        for (int j = 0; j < 2; ++j) {
            int r0 = row0 + wm * 32 + i * 16 + quad * 4;
            int c = col0 + wn * 32 + j * 16 + m16;
            #pragma unroll
            for (int reg = 0; reg < 4; ++reg)
                C[(size_t)(r0 + reg) * 512 + c] = acc[i][j][reg];
        }
}

extern "C" void kernel_launch(void* const* d_in, const int* in_sizes, int n_in,
                              void* d_out, int out_size, void* d_ws, size_t ws_size,
                              hipStream_t stream) {
    const float* queries    = (const float*)d_in[0];
    const float* stat_keys  = (const float*)d_in[1];
    const float* token_keys = (const float*)d_in[2];
    const float* values     = (const float*)d_in[3];
    const int*   valid_lens = (const int*)d_in[4];
    const float* Wq_stat    = (const float*)d_in[5];
    const float* Wq_token   = (const float*)d_in[6];
    const float* Wk_stat    = (const float*)d_in[7];
    const float* Wk_token   = (const float*)d_in[8];
    const float* Wv         = (const float*)d_in[9];
    const float* Wo         = (const float*)d_in[10];

    char* w = (char*)d_ws;
    ushort* wT      = (ushort*)(w + 0);          // 6 x (hi+lo) x 262144 ush = 6 MB
    float*  q_stat  = (float*)(w + 6291456);     // 1 MB fp32 [512][512]
    float*  k_stat  = (float*)(w + 7340032);     // 1 MB
    float*  q_tokf  = (float*)(w + 8388608);     // 1 MB
    ushort* k_tok   = (ushort*)(w + 9437184);    // 8 MB bf16 [8192][512]
    ushort* v_projT = (ushort*)(w + 17825792);   // 8 MB bf16 [64][64][1024]
    ushort* ctx_hi  = (ushort*)(w + 26214400);   // 512 KB
    ushort* ctx_lo  = ctx_hi + 262144;           // 512 KB

    // weight order in wT: 0=Wq_stat 1=Wk_stat 2=Wq_token 3=Wk_token 4=Wv 5=Wo
    ushort* wo_h = wT + 5 * 524288, *wo_l = wo_h + 262144;

    // K1: weight transpose + hi/lo split (once)
    conv_w<<<dim3(16, 16, 6), 256, 0, stream>>>(
        Wq_stat, Wk_stat, Wq_token, Wk_token, Wv, Wo, wT);

    // K2: all five projection GEMMs, one launch
    gemm_all<<<704, 256, 0, stream>>>(
        queries, stat_keys, token_keys, values, wT,
        q_stat, k_stat, q_tokf, k_tok, v_projT);

    // K3: stat top-8 + softmax + dense token attention -> ctx hi/lo
    fused_attend<<<256, 256, 0, stream>>>(
        q_tokf, q_stat, k_stat, valid_lens, k_tok, v_projT, ctx_hi, ctx_lo);

    // K4: output projection
    gemm_out<<<dim3(8, 8), 256, 0, stream>>>(
        ctx_hi, ctx_lo, wo_h, wo_l, (float*)d_out);
}

// Round 5
// 221.834 us; speedup vs baseline: 1.1372x; 1.0007x over previous
//
#include <hip/hip_runtime.h>
#include <hip/hip_bf16.h>

#define STAT_K 8
#define TOKEN_K 16

typedef short bf16x8 __attribute__((ext_vector_type(8)));
typedef float f32x4 __attribute__((ext_vector_type(4)));

__device__ inline ushort f2bf_rne(float x) {
    union { float f; unsigned u; } v; v.f = x;
    unsigned r = v.u + 0x7fff + ((v.u >> 16) & 1);
    return (ushort)(r >> 16);
}
__device__ inline float bf2f(ushort h) {
    union { unsigned u; float f; } v; v.u = ((unsigned)h) << 16;
    return v.f;
}

// ---------------------------------------------------------------------------
// K1: transpose + hi/lo-split the 6 weight matrices (one 6 MB sweep).
// wT layout per z: hi[n][k] (262144 ush) then lo[n][k].
// ---------------------------------------------------------------------------
__global__ __launch_bounds__(256) void conv_w(
    const float* w0, const float* w1, const float* w2,
    const float* w3, const float* w4, const float* w5,
    ushort* wT)
{
    const int z = blockIdx.z;
    const float* srcs[6] = {w0, w1, w2, w3, w4, w5};
    const float* src = srcs[z];
    ushort* hi = wT + (size_t)z * 524288;
    ushort* lo = hi + 262144;
    __shared__ float t[32][33];
    const int c0 = blockIdx.x * 32, r0 = blockIdx.y * 32;
    const int tx = threadIdx.x & 31, ty = threadIdx.x >> 5;  // ty 0..7
    #pragma unroll
    for (int i = 0; i < 4; ++i)
        t[ty + 8 * i][tx] = src[(r0 + ty + 8 * i) * 512 + c0 + tx];
    __syncthreads();
    #pragma unroll
    for (int i = 0; i < 4; ++i) {
        float x = t[tx][ty + 8 * i];
        ushort h = f2bf_rne(x);
        int o = (c0 + ty + 8 * i) * 512 + r0 + tx;
        hi[o] = h;
        lo[o] = f2bf_rne(x - bf2f(h));
    }
}

// ---------------------------------------------------------------------------
// K2: all five projection GEMMs in one launch (verified round 4).
// ---------------------------------------------------------------------------
__global__ __launch_bounds__(256) void gemm_all(
    const float* __restrict__ queries, const float* __restrict__ stat_keys,
    const float* __restrict__ token_keys, const float* __restrict__ values,
    const ushort* __restrict__ wT,
    float* __restrict__ q_stat, float* __restrict__ k_stat,
    float* __restrict__ q_tokf,
    ushort* __restrict__ k_tok, ushort* __restrict__ v_projT)
{
    __shared__ ushort smem[12800];   // 25.6 KB, unioned between variants
    const int tid = threadIdx.x;
    const int bid = blockIdx.x;
    const int wave = tid >> 6, lane = tid & 63;
    const int m16 = lane & 15, quad = lane >> 4;
    const int srow = tid >> 2, schunk = tid & 3;

    if (bid < 192) {
        // ---------------- split-precision 64x64 variant ----------------
        const int z = bid >> 6, t = bid & 63;
        const int row0 = (t >> 3) * 64, col0 = (t & 7) * 64;
        const float* A = (z == 1) ? stat_keys : queries;
        const ushort* Bh = wT + (size_t)z * 524288;
        const ushort* Bl = Bh + 262144;
        float* C = (z == 0) ? q_stat : (z == 1) ? k_stat : q_tokf;

        ushort* As_hi = smem;            // [64][40]
        ushort* As_lo = smem + 2560;
        ushort* Bs_hi = smem + 5120;
        ushort* Bs_lo = smem + 7680;
        const int wm = wave & 1, wn = wave >> 1;

        f32x4 acc[2][2];
        #pragma unroll
        for (int i = 0; i < 2; ++i)
            #pragma unroll
            for (int j = 0; j < 2; ++j)
                #pragma unroll
                for (int r = 0; r < 4; ++r) acc[i][j][r] = 0.f;

        for (int k0 = 0; k0 < 512; k0 += 32) {
            const float* ap = A + (size_t)(row0 + srow) * 512 + k0 + schunk * 8;
            float4 x0 = ((const float4*)ap)[0];
            float4 x1 = ((const float4*)ap)[1];
            ushort4 h0, l0, h1, l1;
            h0.x = f2bf_rne(x0.x); l0.x = f2bf_rne(x0.x - bf2f(h0.x));
            h0.y = f2bf_rne(x0.y); l0.y = f2bf_rne(x0.y - bf2f(h0.y));
            h0.z = f2bf_rne(x0.z); l0.z = f2bf_rne(x0.z - bf2f(h0.z));
            h0.w = f2bf_rne(x0.w); l0.w = f2bf_rne(x0.w - bf2f(h0.w));
            h1.x = f2bf_rne(x1.x); l1.x = f2bf_rne(x1.x - bf2f(h1.x));
            h1.y = f2bf_rne(x1.y); l1.y = f2bf_rne(x1.y - bf2f(h1.y));
            h1.z = f2bf_rne(x1.z); l1.z = f2bf_rne(x1.z - bf2f(h1.z));
            h1.w = f2bf_rne(x1.w); l1.w = f2bf_rne(x1.w - bf2f(h1.w));
            *(ushort4*)&As_hi[srow * 40 + schunk * 8]     = h0;
            *(ushort4*)&As_hi[srow * 40 + schunk * 8 + 4] = h1;
            *(ushort4*)&As_lo[srow * 40 + schunk * 8]     = l0;
            *(ushort4*)&As_lo[srow * 40 + schunk * 8 + 4] = l1;

            const size_t boff = (size_t)(col0 + srow) * 512 + k0 + schunk * 8;
            *(uint4*)&Bs_hi[srow * 40 + schunk * 8] = *(const uint4*)(Bh + boff);
            *(uint4*)&Bs_lo[srow * 40 + schunk * 8] = *(const uint4*)(Bl + boff);
            __syncthreads();

            bf16x8 af[2], bfv[2], afl[2], bfl[2];
            #pragma unroll
            for (int i = 0; i < 2; ++i) {
                af[i]  = *(const bf16x8*)&As_hi[(wm * 32 + i * 16 + m16) * 40 + quad * 8];
                bfv[i] = *(const bf16x8*)&Bs_hi[(wn * 32 + i * 16 + m16) * 40 + quad * 8];
                afl[i] = *(const bf16x8*)&As_lo[(wm * 32 + i * 16 + m16) * 40 + quad * 8];
                bfl[i] = *(const bf16x8*)&Bs_lo[(wn * 32 + i * 16 + m16) * 40 + quad * 8];
            }
            #pragma unroll
            for (int i = 0; i < 2; ++i)
                #pragma unroll
                for (int j = 0; j < 2; ++j) {
                    acc[i][j] = __builtin_amdgcn_mfma_f32_16x16x32_bf16(af[i],  bfv[j], acc[i][j], 0, 0, 0);
                    acc[i][j] = __builtin_amdgcn_mfma_f32_16x16x32_bf16(af[i],  bfl[j], acc[i][j], 0, 0, 0);
                    acc[i][j] = __builtin_amdgcn_mfma_f32_16x16x32_bf16(afl[i], bfv[j], acc[i][j], 0, 0, 0);
                }
            __syncthreads();
        }

        #pragma unroll
        for (int i = 0; i < 2; ++i)
            #pragma unroll
            for (int j = 0; j < 2; ++j) {
                int r0 = row0 + wm * 32 + i * 16 + quad * 4;
                int c = col0 + wn * 32 + j * 16 + m16;
                #pragma unroll
                for (int reg = 0; reg < 4; ++reg)
                    C[(size_t)(r0 + reg) * 512 + c] = acc[i][j][reg];
            }
    } else {
        // ---------------- token-path 64x256 variant (hi only) ----------------
        const int u = bid - 192;
        const int z2 = u >> 8, vv = u & 255;
        const int col0 = (vv & 1) * 256, row0 = (vv >> 1) * 64;
        const float* A = z2 ? values : token_keys;
        const ushort* Bh = wT + (size_t)(z2 ? 4 : 3) * 524288;

        ushort* As = smem;            // [64][40]
        ushort* Bs = smem + 2560;     // [256][40]
        const int r = row0 + srow;
        const size_t arow = (size_t)((r >> 4) * 64 + 48 + (r & 15)) * 512;

        f32x4 acc[4][4];
        #pragma unroll
        for (int i = 0; i < 4; ++i)
            #pragma unroll
            for (int j = 0; j < 4; ++j)
                #pragma unroll
                for (int rr = 0; rr < 4; ++rr) acc[i][j][rr] = 0.f;

        for (int k0 = 0; k0 < 512; k0 += 32) {
            const float* ap = A + arow + k0 + schunk * 8;
            float4 x0 = ((const float4*)ap)[0];
            float4 x1 = ((const float4*)ap)[1];
            ushort4 h0, h1;
            h0.x = f2bf_rne(x0.x); h0.y = f2bf_rne(x0.y);
            h0.z = f2bf_rne(x0.z); h0.w = f2bf_rne(x0.w);
            h1.x = f2bf_rne(x1.x); h1.y = f2bf_rne(x1.y);
            h1.z = f2bf_rne(x1.z); h1.w = f2bf_rne(x1.w);
            *(ushort4*)&As[srow * 40 + schunk * 8]     = h0;
            *(ushort4*)&As[srow * 40 + schunk * 8 + 4] = h1;

            #pragma unroll
            for (int i = 0; i < 4; ++i) {
                int v = tid + i * 256;
                int brow = v >> 2, bchunk = v & 3;
                *(uint4*)&Bs[brow * 40 + bchunk * 8] =
                    *(const uint4*)(Bh + (size_t)(col0 + brow) * 512 + k0 + bchunk * 8);
            }
            __syncthreads();

            bf16x8 af[4], bf[4];
            #pragma unroll
            for (int i = 0; i < 4; ++i) {
                af[i] = *(const bf16x8*)&As[(i * 16 + m16) * 40 + quad * 8];
                bf[i] = *(const bf16x8*)&Bs[(wave * 64 + i * 16 + m16) * 40 + quad * 8];
            }
            #pragma unroll
            for (int i = 0; i < 4; ++i)
                #pragma unroll
                for (int j = 0; j < 4; ++j)
                    acc[i][j] = __builtin_amdgcn_mfma_f32_16x16x32_bf16(af[i], bf[j], acc[i][j], 0, 0, 0);
            __syncthreads();
        }

        #pragma unroll
        for (int i = 0; i < 4; ++i)
            #pragma unroll
            for (int j = 0; j < 4; ++j) {
                int rg = row0 + i * 16 + quad * 4;
                int c = col0 + wave * 64 + j * 16 + m16;
                if (z2 == 0) {
                    #pragma unroll
                    for (int reg = 0; reg < 4; ++reg)
                        k_tok[(size_t)(rg + reg) * 512 + c] = f2bf_rne(acc[i][j][reg]);
                } else {
                    int bb2 = rg >> 10, st = rg & 1023;
                    int hh = c >> 6, dd = c & 63;
                    ushort4 o4;
                    o4.x = f2bf_rne(acc[i][j][0]);
                    o4.y = f2bf_rne(acc[i][j][1]);
                    o4.z = f2bf_rne(acc[i][j][2]);
                    o4.w = f2bf_rne(acc[i][j][3]);
                    *(ushort4*)(v_projT + (((size_t)((bb2 * 8 + hh) * 64 + dd)) << 10) + st) = o4;
                }
            }
    }
}

// ---------------------------------------------------------------------------
// K3: stat scores + valid-len mask + top-8 + softmax -> DENSE stat_w
// [4096][64] (zero at non-selected segments). One wave per (b,h,q).
// (verified round 1)
// ---------------------------------------------------------------------------
__global__ __launch_bounds__(64) void stat_topk(
    const float* __restrict__ q_stat, const float* __restrict__ k_stat,
    const int* __restrict__ valid_lens,
    float* __restrict__ stat_wd)
{
    const int bid = blockIdx.x;           // b*512 + h*64 + q
    const int b = bid >> 9;
    const int hq = bid & 511;
    const int h = hq >> 6;
    const int q = hq & 63;
    const int lane = threadIdx.x;         // segment index s

    __shared__ float sq[64];
    sq[lane] = q_stat[(b * 64 + q) * 512 + h * 64 + lane];
    __syncthreads();

    const float4* kr = (const float4*)(k_stat + (b * 64 + lane) * 512 + h * 64);
    const float4* sq4 = (const float4*)sq;
    float sc = 0.f;
    #pragma unroll
    for (int i = 0; i < 16; ++i) {
        float4 a = sq4[i], kk = kr[i];
        sc += a.x * kk.x + a.y * kk.y + a.z * kk.z + a.w * kk.w;
    }
    sc *= 0.125f;
    if (lane >= valid_lens[b]) sc = -1e6f;

    const float sc_keep = sc;
    float my = sc;
    bool picked = false;
    float m0 = 0.f, den = 0.f;
    #pragma unroll
    for (int j = 0; j < STAT_K; ++j) {
        float v = my;
        int idx = lane;
        #pragma unroll
        for (int off = 32; off > 0; off >>= 1) {
            float ov = __shfl_down(v, off);
            int   oi = __shfl_down(idx, off);
            if (ov > v || (ov == v && oi < idx)) { v = ov; idx = oi; }
        }
        v = __shfl(v, 0);
        idx = __shfl(idx, 0);
        if (j == 0) m0 = v;
        den += __expf(v - m0);
        if (lane == idx) { my = -3e38f; picked = true; }
    }
    stat_wd[(size_t)bid * 64 + lane] = picked ? __expf(sc_keep - m0) / den : 0.f;
}

// ---------------------------------------------------------------------------
// K4: dense MFMA token attention, chunk-parallel. One block per
// (b,h,16-q slice, 16-segment chunk) -> 1024 blocks, 4 waves each.
// Writes fp32 partial [ch][b*64+q][h*64+d]; gemm_out sums the 4 chunks.
// ---------------------------------------------------------------------------
__global__ __launch_bounds__(256) void tok_attend(
    const float* __restrict__ q_tokf, const ushort* __restrict__ k_tok,
    const ushort* __restrict__ v_projT, const float* __restrict__ stat_wd,
    float* __restrict__ part)
{
    const int bid = blockIdx.x;
    const int ch = bid & 3, qb = (bid >> 2) & 3, bh = bid >> 4;
    const int b = bh >> 3, h = bh & 7;
    const int tid = threadIdx.x, wave = tid >> 6, lane = tid & 63;
    const int l15 = lane & 15, g = lane >> 4;
    const int q0 = qb * 16;

    __shared__ ushort qs_hi[16][72], qs_lo[16][72];       // q_tok hi/lo
    __shared__ float  sw16[16][17];                       // stat_w slice
    __shared__ ushort comb_hi[16][264], comb_lo[16][264]; // [q][st], swizzled

    // ---- stage q slice (fp32 -> hi/lo bf16) and stat_w slice
    {
        const int qq = tid >> 4, c = (tid & 15) * 4;
        float4 x = *(const float4*)(q_tokf + (size_t)(b * 64 + q0 + qq) * 512 + h * 64 + c);
        ushort4 hx, lx;
        hx.x = f2bf_rne(x.x); lx.x = f2bf_rne(x.x - bf2f(hx.x));
        hx.y = f2bf_rne(x.y); lx.y = f2bf_rne(x.y - bf2f(hx.y));
        hx.z = f2bf_rne(x.z); lx.z = f2bf_rne(x.z - bf2f(hx.z));
        hx.w = f2bf_rne(x.w); lx.w = f2bf_rne(x.w - bf2f(hx.w));
        *(ushort4*)&qs_hi[qq][c] = hx;
        *(ushort4*)&qs_lo[qq][c] = lx;
        sw16[tid >> 4][tid & 15] =
            stat_wd[(size_t)bh * 4096 + (q0 + (tid >> 4)) * 64 + ch * 16 + (tid & 15)];
    }
    __syncthreads();

    const int swz = (l15 & 7) << 4;

    // ---- QK: this wave computes 4 segments (64 st) x 16 q
    const int sbase = ch * 16 + wave * 4;
    f32x4 sc[4];
    #pragma unroll
    for (int mt = 0; mt < 4; ++mt)
        #pragma unroll
        for (int rr = 0; rr < 4; ++rr) sc[mt][rr] = 0.f;

    #pragma unroll
    for (int ks2 = 0; ks2 < 2; ++ks2) {
        bf16x8 bhf = *(const bf16x8*)&qs_hi[l15][ks2 * 32 + g * 8];
        bf16x8 blf = *(const bf16x8*)&qs_lo[l15][ks2 * 32 + g * 8];
        #pragma unroll
        for (int mt = 0; mt < 4; ++mt) {
            const ushort* kp = k_tok +
                (size_t)(b * 1024 + (sbase + mt) * 16 + l15) * 512 + h * 64 + ks2 * 32 + g * 8;
            bf16x8 a = *(const bf16x8*)kp;
            sc[mt] = __builtin_amdgcn_mfma_f32_16x16x32_bf16(a, bhf, sc[mt], 0, 0, 0);
            sc[mt] = __builtin_amdgcn_mfma_f32_16x16x32_bf16(a, blf, sc[mt], 0, 0, 0);
        }
    }

    // ---- per-segment softmax over 16 tokens + comb write (hi/lo)
    #pragma unroll
    for (int mt = 0; mt < 4; ++mt) {
        float e0 = __expf(sc[mt][0] * 0.125f);
        float e1 = __expf(sc[mt][1] * 0.125f);
        float e2 = __expf(sc[mt][2] * 0.125f);
        float e3 = __expf(sc[mt][3] * 0.125f);
        float den = e0 + e1 + e2 + e3;
        den += __shfl_xor(den, 16);
        den += __shfl_xor(den, 32);
        float scl = sw16[l15][wave * 4 + mt] / den;
        ushort4 hx, lx;
        float c0 = e0 * scl; hx.x = f2bf_rne(c0); lx.x = f2bf_rne(c0 - bf2f(hx.x));
        float c1 = e1 * scl; hx.y = f2bf_rne(c1); lx.y = f2bf_rne(c1 - bf2f(hx.y));
        float c2 = e2 * scl; hx.z = f2bf_rne(c2); lx.z = f2bf_rne(c2 - bf2f(hx.z));
        float c3 = e3 * scl; hx.w = f2bf_rne(c3); lx.w = f2bf_rne(c3 - bf2f(hx.w));
        int colb = (((wave * 4 + mt) * 16 + g * 4) * 2) ^ swz;
        *(ushort4*)((char*)&comb_hi[l15][0] + colb) = hx;
        *(ushort4*)((char*)&comb_lo[l15][0] + colb) = lx;
    }
    __syncthreads();

    // ---- PV over this chunk (K = 256 st); wave owns 16-d block
    f32x4 accd;
    #pragma unroll
    for (int rr = 0; rr < 4; ++rr) accd[rr] = 0.f;

    #pragma unroll
    for (int ks2 = 0; ks2 < 8; ++ks2) {
        const ushort* vp = v_projT +
            ((size_t)(bh * 64 + wave * 16 + l15) << 10) + ch * 256 + ks2 * 32 + g * 8;
        bf16x8 a = *(const bf16x8*)vp;
        int colb = ((ks2 * 32 + g * 8) * 2) ^ swz;
        bf16x8 bhf = *(const bf16x8*)((const char*)&comb_hi[l15][0] + colb);
        bf16x8 blf = *(const bf16x8*)((const char*)&comb_lo[l15][0] + colb);
        accd = __builtin_amdgcn_mfma_f32_16x16x32_bf16(a, bhf, accd, 0, 0, 0);
        accd = __builtin_amdgcn_mfma_f32_16x16x32_bf16(a, blf, accd, 0, 0, 0);
    }

    // ---- partial write: lane holds d = wave*16 + g*4 + rr, q = q0 + l15
    *(f32x4*)(part + ((size_t)(ch * 512 + b * 64 + q0 + l15) * 512)
                    + h * 64 + wave * 16 + g * 4) = accd;
}

// ---------------------------------------------------------------------------
// K5: out = (sum_ch part[ch]) @ Wo(hi/lo planes), 512x512x512 -> fp32.
// A is summed + hi/lo split in registers during staging.
// ---------------------------------------------------------------------------
__global__ __launch_bounds__(256) void gemm_out(
    const float* __restrict__ part,
    const ushort* __restrict__ Bh, const ushort* __restrict__ Bl,
    float* __restrict__ C)
{
    __shared__ ushort As[2][64][40];
    __shared__ ushort Bs[2][64][40];
    const int tid = threadIdx.x;
    const int row0 = blockIdx.y * 64, col0 = blockIdx.x * 64;
    const int wave = tid >> 6, lane = tid & 63;
    const int wm = wave & 1, wn = wave >> 1;
    const int m16 = lane & 15, quad = lane >> 4;
    const int srow = tid >> 2, schunk = tid & 3;

    f32x4 acc[2][2];
    #pragma unroll
    for (int i = 0; i < 2; ++i)
        #pragma unroll
        for (int j = 0; j < 2; ++j)
            #pragma unroll
            for (int r = 0; r < 4; ++r) acc[i][j][r] = 0.f;

    for (int k0 = 0; k0 < 512; k0 += 32) {
        // A: sum 4 chunk partials, split hi/lo
        const float* pb = part + (size_t)(row0 + srow) * 512 + k0 + schunk * 8;
        float s[8];
        #pragma unroll
        for (int e = 0; e < 8; ++e) s[e] = 0.f;
        #pragma unroll
        for (int c = 0; c < 4; ++c) {
            const float4* p4 = (const float4*)(pb + (size_t)c * 262144);
            float4 a0 = p4[0], a1 = p4[1];
            s[0] += a0.x; s[1] += a0.y; s[2] += a0.z; s[3] += a0.w;
            s[4] += a1.x; s[5] += a1.y; s[6] += a1.z; s[7] += a1.w;
        }
        ushort hv[8], lv[8];
        #pragma unroll
        for (int e = 0; e < 8; ++e) {
            hv[e] = f2bf_rne(s[e]);
            lv[e] = f2bf_rne(s[e] - bf2f(hv[e]));
        }
        *(ushort4*)&As[0][srow][schunk * 8]     = *(ushort4*)&hv[0];
        *(ushort4*)&As[0][srow][schunk * 8 + 4] = *(ushort4*)&hv[4];
        *(ushort4*)&As[1][srow][schunk * 8]     = *(ushort4*)&lv[0];
        *(ushort4*)&As[1][srow][schunk * 8 + 4] = *(ushort4*)&lv[4];

        const size_t boff = (size_t)(col0 + srow) * 512 + k0 + schunk * 8;
        *(uint4*)&Bs[0][srow][schunk * 8] = *(const uint4*)(Bh + boff);
        *(uint4*)&Bs[1][srow][schunk * 8] = *(const uint4*)(Bl + boff);
        __syncthreads();

        bf16x8 af[2], bf[2], afl[2], bfl[2];
        #pragma unroll
        for (int i = 0; i < 2; ++i) {
            af[i]  = *(const bf16x8*)&As[0][wm * 32 + i * 16 + m16][quad * 8];
            bf[i]  = *(const bf16x8*)&Bs[0][wn * 32 + i * 16 + m16][quad * 8];
            afl[i] = *(const bf16x8*)&As[1][wm * 32 + i * 16 + m16][quad * 8];
            bfl[i] = *(const bf16x8*)&Bs[1][wn * 32 + i * 16 + m16][quad * 8];
        }
        #pragma unroll
        for (int i = 0; i < 2; ++i)
            #pragma unroll
            for (int j = 0; j < 2; ++j) {
                acc[i][j] = __builtin_amdgcn_mfma_f32_16x16x32_bf16(af[i], bf[j], acc[i][j], 0, 0, 0);
                acc[i][j] = __builtin_amdgcn_mfma_f32_16x16x32_bf16(af[i], bfl[j], acc[i][j], 0, 0, 0);
                acc[i][j] = __builtin_amdgcn_mfma_f32_16x16x32_bf16(afl[i], bf[j], acc[i][j], 0, 0, 0);
            }
        __syncthreads();
    }

    #pragma unroll
    for (int i = 0; i < 2; ++i)
        #pragma unroll
        for (int j = 0; j < 2; ++j) {
            int r0 = row0 + wm * 32 + i * 16 + quad * 4;
            int c = col0 + wn * 32 + j * 16 + m16;
            #pragma unroll
            for (int reg = 0; reg < 4; ++reg)
                C[(size_t)(r0 + reg) * 512 + c] = acc[i][j][reg];
        }
}

extern "C" void kernel_launch(void* const* d_in, const int* in_sizes, int n_in,
                              void* d_out, int out_size, void* d_ws, size_t ws_size,
                              hipStream_t stream) {
    const float* queries    = (const float*)d_in[0];
    const float* stat_keys  = (const float*)d_in[1];
    const float* token_keys = (const float*)d_in[2];
    const float* values     = (const float*)d_in[3];
    const int*   valid_lens = (const int*)d_in[4];
    const float* Wq_stat    = (const float*)d_in[5];
    const float* Wq_token   = (const float*)d_in[6];
    const float* Wk_stat    = (const float*)d_in[7];
    const float* Wk_token   = (const float*)d_in[8];
    const float* Wv         = (const float*)d_in[9];
    const float* Wo         = (const float*)d_in[10];

    char* w = (char*)d_ws;
    ushort* wT      = (ushort*)(w + 0);          // 6 MB: 6 x (hi+lo) x 262144
    float*  q_stat  = (float*)(w + 6291456);     // 1 MB fp32 [512][512]
    float*  k_stat  = (float*)(w + 7340032);     // 1 MB
    float*  q_tokf  = (float*)(w + 8388608);     // 1 MB
    ushort* k_tok   = (ushort*)(w + 9437184);    // 8 MB bf16 [8192][512]
    ushort* v_projT = (ushort*)(w + 17825792);   // 8 MB bf16 [64][64][1024]
    float*  stat_wd = (float*)(w + 26214400);    // 1 MB dense [4096][64]
    float*  part    = (float*)(w + 27262976);    // 4 MB fp32 [4][512][512]

    // weight order in wT: 0=Wq_stat 1=Wk_stat 2=Wq_token 3=Wk_token 4=Wv 5=Wo
    ushort* wo_h = wT + 5 * 524288, *wo_l = wo_h + 262144;

    // K1: weight transpose + hi/lo split (once)
    conv_w<<<dim3(16, 16, 6), 256, 0, stream>>>(
        Wq_stat, Wk_stat, Wq_token, Wk_token, Wv, Wo, wT);

    // K2: all five projection GEMMs, one launch
    gemm_all<<<704, 256, 0, stream>>>(
        queries, stat_keys, token_keys, values, wT,
        q_stat, k_stat, q_tokf, k_tok, v_projT);

    // K3: stat top-8 + softmax -> dense stat_w
    stat_topk<<<4096, 64, 0, stream>>>(q_stat, k_stat, valid_lens, stat_wd);

    // K4: chunk-parallel dense token attention -> fp32 partials
    tok_attend<<<1024, 256, 0, stream>>>(q_tokf, k_tok, v_projT, stat_wd, part);

    // K5: output projection (sums partials in A-staging)
    gemm_out<<<dim3(8, 8), 256, 0, stream>>>(part, wo_h, wo_l, (float*)d_out);
}